// Round 7
// baseline (217.730 us; speedup 1.0000x reference)
//
#include <hip/hip_runtime.h>
#include <stdint.h>

#define EPSN 1e-9f

// Wave-level LDS fence (rule #18: sched_barrier after waitcnt).
#define LDS_FENCE()                                        \
  do {                                                     \
    asm volatile("s_waitcnt lgkmcnt(0)" ::: "memory");     \
    __builtin_amdgcn_sched_barrier(0);                     \
  } while (0)

// ---------------------------------------------------------------------------
// ws layout (floats): [0) inv1_1 [4][3072]   [12288) inv2_1 [4][3072]
// ---------------------------------------------------------------------------
__global__ __launch_bounds__(256) void norms1_kernel(
    const float* __restrict__ x1_1, const float* __restrict__ x2_1,
    float* __restrict__ ws) {
  int p = blockIdx.x * 256 + threadIdx.x;     // 24576 total
  const float* src = (p < 12288) ? x1_1 : x2_1;
  int q = (p < 12288) ? p : p - 12288;        // 12288 is NOT pow2
  long base = (long)(q / 3072) * 786432 + (q % 3072);
  float ss = 0.f;
#pragma unroll 8
  for (int c = 0; c < 256; ++c) { float v = src[base + (long)c * 3072]; ss += v * v; }
  ws[p] = 1.f / (sqrtf(ss) + EPSN);
}

// ---------------------------------------------------------------------------
// Level 0 (stride 4, d=1), norms fused. Block=(b,i,u), XCD-swizzled.
// Shuffle-based inner loop (no LDS in the hot loop). Lane=j.  (unchanged)
// ---------------------------------------------------------------------------
__global__ __launch_bounds__(256) void corr0_kernel(
    const float* __restrict__ x1, const float* __restrict__ x2,
    float* __restrict__ out) {
  int bx = blockIdx.x;
  int L = (bx & 7) * 216 + (bx >> 3);         // 1728 = 8 * 216 (bijective)
  int u = L % 9, i = (L / 9) % 48, b = L / 432;
  int y = 4 * i + u - 4;
  int tid = threadIdx.x;
  long ob = (long)b * 1741824 + (long)u * 27648 + (long)i * 64;
  if (y < 0 || y >= 192) {
    for (int idx = tid; idx < 576; idx += 256)
      out[ob + (idx >> 6) * 3072 + (idx & 63)] = 0.f;
    return;
  }
  __shared__ float red[4][14][64];
  __shared__ float inv2s[264];                 // pads [0..3],[260..263] = 0
  __shared__ float inv1s[64];
  int w = tid >> 6, lane = tid & 63;
  float acc4 = 0.f, acc5 = 0.f, acc6 = 0.f, acc7 = 0.f;
  float aL0 = 0.f, aL1 = 0.f, aL2 = 0.f, aL3 = 0.f, a8 = 0.f;
  float sq0 = 0.f, sq1 = 0.f, sq2 = 0.f, sq3 = 0.f, s1 = 0.f;
  const float* x2row = x2 + (long)b * 12582912 + (long)y * 256 + 4 * lane;
  const float* x1p   = x1 + (long)b * 12582912 + (long)(4 * i) * 256 + 4 * lane;
#pragma unroll 8
  for (int cc = 0; cc < 64; ++cc) {
    long off = (long)(w * 64 + cc) * 49152;
    float4 f = *reinterpret_cast<const float4*>(x2row + off);
    float xv = x1p[off];
    float xr = __shfl_down(xv, 1);            // x1 of lane j+1
    float xl = __shfl_up(xv, 1);              // x1 of lane j-1
    sq0 += f.x * f.x; sq1 += f.y * f.y; sq2 += f.z * f.z; sq3 += f.w * f.w;
    s1  += xv * xv;
    aL0 += xr * f.x; aL1 += xr * f.y; aL2 += xr * f.z; aL3 += xr * f.w;
    acc4 += xv * f.x; acc5 += xv * f.y; acc6 += xv * f.z; acc7 += xv * f.w;
    a8  += xl * f.x;
  }
  // realign: acc[v<4](j) lives at lane j-1; acc[8](j) lives at lane j+1.
  float o0 = __shfl_up(aL0, 1), o1 = __shfl_up(aL1, 1);
  float o2 = __shfl_up(aL2, 1), o3 = __shfl_up(aL3, 1);
  float o8 = __shfl_down(a8, 1);
  // (lane-0 / lane-63 stale values map to OOB cols -> zeroed by inv2s pads)
  red[w][0][lane] = o0;   red[w][1][lane] = o1;   red[w][2][lane] = o2;
  red[w][3][lane] = o3;   red[w][4][lane] = acc4; red[w][5][lane] = acc5;
  red[w][6][lane] = acc6; red[w][7][lane] = acc7; red[w][8][lane] = o8;
  red[w][9][lane] = sq0;  red[w][10][lane] = sq1; red[w][11][lane] = sq2;
  red[w][12][lane] = sq3; red[w][13][lane] = s1;
  __syncthreads();
  {
    int comp = tid & 3, jj = tid >> 2;        // col = tid (0..255)
    float ss = red[0][9 + comp][jj] + red[1][9 + comp][jj] +
               red[2][9 + comp][jj] + red[3][9 + comp][jj];
    inv2s[4 + tid] = 1.f / (sqrtf(ss) + EPSN);
    if (tid < 4) { inv2s[tid] = 0.f; inv2s[260 + tid] = 0.f; }
    if (tid < 64) {
      float t = red[0][13][tid] + red[1][13][tid] +
                red[2][13][tid] + red[3][13][tid];
      inv1s[tid] = 1.f / (sqrtf(t) + EPSN);
    }
  }
  __syncthreads();
  for (int idx = tid; idx < 576; idx += 256) {
    int v = idx >> 6, j = idx & 63;
    float s = red[0][v][j] + red[1][v][j] + red[2][v][j] + red[3][v][j];
    out[ob + v * 3072 + j] = s * inv1s[j] * inv2s[4 * j + v];  // col=4j+v-4
  }
}

// ---------------------------------------------------------------------------
// Level 1 restructured: 1 wave per (b, i, dI, u-group-of-3). 3456 blocks.
// Wave stages its 3 x2 rows bf16x2-packed in LDS [3][192] uint4 (zero-padded
// +-64 cols, init once), amortizing x1/x2 row reads 3x vs per-u blocks.
// Math identical to the round-2/6 passing kernel.
// ---------------------------------------------------------------------------
__global__ __launch_bounds__(64) void corr1_kernel(
    const float* __restrict__ x1, const float* __restrict__ x2,
    const float* __restrict__ ws, float* __restrict__ out) {
  int bx = blockIdx.x;
  int L = (bx & 7) * 432 + (bx >> 3);         // 3456 = 8 * 432 (bijective)
  int g = L % 3, dI = (L / 3) % 6, i = (L / 18) % 48, b = L / 864;
  const int dils[6] = {1, 2, 3, 5, 9, 16};
  int d = dils[dI];
  int lane = threadIdx.x;
  long obase = (long)b * 1741824 + (long)(1 + dI) * 248832 + (long)i * 64 + lane;

  int yr[3]; bool yv[3];
#pragma unroll
  for (int r = 0; r < 3; ++r) {
    int u = 3 * g + r;
    yr[r] = i + (u - 4) * d;
    yv[r] = (yr[r] >= 0 && yr[r] < 48);
  }
  __shared__ uint4 x2t[3 * 192];              // 9216 B
#pragma unroll
  for (int t = 0; t < 9; ++t) x2t[t * 64 + lane] = make_uint4(0, 0, 0, 0);

  const float* x1row = x1 + (long)b * 786432 + (long)i * 64 + lane;
  const float* x2r[3];
#pragma unroll
  for (int r = 0; r < 3; ++r)
    x2r[r] = x2 + (long)b * 786432 + (long)(yv[r] ? yr[r] : 0) * 64 + lane;

  float acc[3][9];
#pragma unroll
  for (int r = 0; r < 3; ++r)
#pragma unroll
    for (int v = 0; v < 9; ++v) acc[r][v] = 0.f;

#pragma unroll 1
  for (int k = 0; k < 32; ++k) {
    long co = (long)k * 8 * 3072;
    // stage 3 rows (8 ch each, bf16x2-packed)
#pragma unroll
    for (int r = 0; r < 3; ++r) {
      if (yv[r]) {
        uint32_t xb[8];
#pragma unroll
        for (int cc = 0; cc < 8; ++cc)
          xb[cc] = __float_as_uint(x2r[r][co + (long)cc * 3072]) + 0x8000u;
        uint4 pk;
        pk.x = (xb[0] >> 16) | (xb[1] & 0xffff0000u);
        pk.y = (xb[2] >> 16) | (xb[3] & 0xffff0000u);
        pk.z = (xb[4] >> 16) | (xb[5] & 0xffff0000u);
        pk.w = (xb[6] >> 16) | (xb[7] & 0xffff0000u);
        x2t[r * 192 + 64 + lane] = pk;        // pads stay zero
      }
    }
    float x1v[8];
#pragma unroll
    for (int cc = 0; cc < 8; ++cc) x1v[cc] = x1row[co + (long)cc * 3072];
    LDS_FENCE();   // own-wave writes visible before shifted cross-lane reads
#pragma unroll
    for (int r = 0; r < 3; ++r) {
      if (!yv[r]) continue;                   // wave-uniform skip
      const uint4* buf = &x2t[r * 192 + 64 + lane];
#pragma unroll
      for (int v = 0; v < 9; ++v) {
        uint4 q = buf[(v - 4) * d];           // idx in [0,192) always
        float s;
        s  = x1v[0] * __uint_as_float(q.x << 16);
        s += x1v[1] * __uint_as_float(q.x & 0xffff0000u);
        s += x1v[2] * __uint_as_float(q.y << 16);
        s += x1v[3] * __uint_as_float(q.y & 0xffff0000u);
        s += x1v[4] * __uint_as_float(q.z << 16);
        s += x1v[5] * __uint_as_float(q.z & 0xffff0000u);
        s += x1v[6] * __uint_as_float(q.w << 16);
        s += x1v[7] * __uint_as_float(q.w & 0xffff0000u);
        acc[r][v] += s;
      }
    }
    LDS_FENCE();   // reads done before next iteration's overwrite (WAR)
  }

  const float* i1 = ws + b * 3072 + i * 64;
  float inv1 = i1[lane];
#pragma unroll
  for (int r = 0; r < 3; ++r) {
    int u = 3 * g + r;
    long ob = obase + (long)u * 27648;
    if (!yv[r]) {
#pragma unroll
      for (int v = 0; v < 9; ++v) out[ob + v * 3072] = 0.f;
    } else {
      const float* i2 = ws + 12288 + b * 3072 + yr[r] * 64;
#pragma unroll
      for (int v = 0; v < 9; ++v) {
        int col = lane + (v - 4) * d;
        float i2v = (col >= 0 && col < 64) ? i2[col] : 0.f;
        out[ob + v * 3072] = acc[r][v] * inv1 * i2v;
      }
    }
  }
}

extern "C" void kernel_launch(void* const* d_in, const int* in_sizes, int n_in,
                              void* d_out, int out_size, void* d_ws, size_t ws_size,
                              hipStream_t stream) {
  const float* x1_0 = (const float*)d_in[0];
  const float* x1_1 = (const float*)d_in[1];
  const float* x2_0 = (const float*)d_in[2];
  const float* x2_1 = (const float*)d_in[3];
  float* out = (float*)d_out;
  float* ws = (float*)d_ws;                   // 98304 bytes used
  norms1_kernel<<<96, 256, 0, stream>>>(x1_1, x2_1, ws);
  corr0_kernel<<<1728, 256, 0, stream>>>(x1_0, x2_0, out);
  corr1_kernel<<<3456, 64, 0, stream>>>(x1_1, x2_1, ws, out);
}

// Round 8
// 131.752 us; speedup vs baseline: 1.6526x; 1.6526x over previous
//
#include <hip/hip_runtime.h>
#include <stdint.h>

#define EPSN 1e-9f

typedef __fp16 f16x8 __attribute__((ext_vector_type(8)));
typedef float f32x4 __attribute__((ext_vector_type(4)));

// Wave-level LDS fence (rule #18: sched_barrier after waitcnt).
#define LDS_FENCE()                                        \
  do {                                                     \
    asm volatile("s_waitcnt lgkmcnt(0)" ::: "memory");     \
    __builtin_amdgcn_sched_barrier(0);                     \
  } while (0)

// ---------------------------------------------------------------------------
// ws layout: [0) inv1_1 [4][3072] f32  [12288) inv2_1 [4][3072] f32
//            byte 98304: w1h [4][48][64][256] f16 (6291456 B)
//            byte 6389760: w2h same                (6291456 B)
// fast path needs 12681216 B total.
// ---------------------------------------------------------------------------

__global__ __launch_bounds__(256) void norms1_kernel(
    const float* __restrict__ x1_1, const float* __restrict__ x2_1,
    float* __restrict__ ws) {
  int p = blockIdx.x * 256 + threadIdx.x;     // 24576 total
  const float* src = (p < 12288) ? x1_1 : x2_1;
  int q = (p < 12288) ? p : p - 12288;
  long base = (long)(q / 3072) * 786432 + (q % 3072);
  float ss = 0.f;
#pragma unroll 8
  for (int c = 0; c < 256; ++c) { float v = src[base + (long)c * 3072]; ss += v * v; }
  ws[p] = 1.f / (sqrtf(ss) + EPSN);
}

// ---------------------------------------------------------------------------
// Level 0 (stride 4, d=1), norms fused. Block=(b,i,u), XCD-swizzled. Unchanged.
// ---------------------------------------------------------------------------
__global__ __launch_bounds__(256) void corr0_kernel(
    const float* __restrict__ x1, const float* __restrict__ x2,
    float* __restrict__ out) {
  int bx = blockIdx.x;
  int L = (bx & 7) * 216 + (bx >> 3);         // 1728 = 8 * 216 (bijective)
  int u = L % 9, i = (L / 9) % 48, b = L / 432;
  int y = 4 * i + u - 4;
  int tid = threadIdx.x;
  long ob = (long)b * 1741824 + (long)u * 27648 + (long)i * 64;
  if (y < 0 || y >= 192) {
    for (int idx = tid; idx < 576; idx += 256)
      out[ob + (idx >> 6) * 3072 + (idx & 63)] = 0.f;
    return;
  }
  __shared__ float red[4][14][64];
  __shared__ float inv2s[264];
  __shared__ float inv1s[64];
  int w = tid >> 6, lane = tid & 63;
  float acc4 = 0.f, acc5 = 0.f, acc6 = 0.f, acc7 = 0.f;
  float aL0 = 0.f, aL1 = 0.f, aL2 = 0.f, aL3 = 0.f, a8 = 0.f;
  float sq0 = 0.f, sq1 = 0.f, sq2 = 0.f, sq3 = 0.f, s1 = 0.f;
  const float* x2row = x2 + (long)b * 12582912 + (long)y * 256 + 4 * lane;
  const float* x1p   = x1 + (long)b * 12582912 + (long)(4 * i) * 256 + 4 * lane;
#pragma unroll 8
  for (int cc = 0; cc < 64; ++cc) {
    long off = (long)(w * 64 + cc) * 49152;
    float4 f = *reinterpret_cast<const float4*>(x2row + off);
    float xv = x1p[off];
    float xr = __shfl_down(xv, 1);
    float xl = __shfl_up(xv, 1);
    sq0 += f.x * f.x; sq1 += f.y * f.y; sq2 += f.z * f.z; sq3 += f.w * f.w;
    s1  += xv * xv;
    aL0 += xr * f.x; aL1 += xr * f.y; aL2 += xr * f.z; aL3 += xr * f.w;
    acc4 += xv * f.x; acc5 += xv * f.y; acc6 += xv * f.z; acc7 += xv * f.w;
    a8  += xl * f.x;
  }
  float o0 = __shfl_up(aL0, 1), o1 = __shfl_up(aL1, 1);
  float o2 = __shfl_up(aL2, 1), o3 = __shfl_up(aL3, 1);
  float o8 = __shfl_down(a8, 1);
  red[w][0][lane] = o0;   red[w][1][lane] = o1;   red[w][2][lane] = o2;
  red[w][3][lane] = o3;   red[w][4][lane] = acc4; red[w][5][lane] = acc5;
  red[w][6][lane] = acc6; red[w][7][lane] = acc7; red[w][8][lane] = o8;
  red[w][9][lane] = sq0;  red[w][10][lane] = sq1; red[w][11][lane] = sq2;
  red[w][12][lane] = sq3; red[w][13][lane] = s1;
  __syncthreads();
  {
    int comp = tid & 3, jj = tid >> 2;
    float ss = red[0][9 + comp][jj] + red[1][9 + comp][jj] +
               red[2][9 + comp][jj] + red[3][9 + comp][jj];
    inv2s[4 + tid] = 1.f / (sqrtf(ss) + EPSN);
    if (tid < 4) { inv2s[tid] = 0.f; inv2s[260 + tid] = 0.f; }
    if (tid < 64) {
      float t = red[0][13][tid] + red[1][13][tid] +
                red[2][13][tid] + red[3][13][tid];
      inv1s[tid] = 1.f / (sqrtf(t) + EPSN);
    }
  }
  __syncthreads();
  for (int idx = tid; idx < 576; idx += 256) {
    int v = idx >> 6, j = idx & 63;
    float s = red[0][v][j] + red[1][v][j] + red[2][v][j] + red[3][v][j];
    out[ob + v * 3072 + j] = s * inv1s[j] * inv2s[4 * j + v];
  }
}

// ---------------------------------------------------------------------------
// Zero-fill the level-1 output slab (channels 1..6 of each b): 1492992 float4.
// ---------------------------------------------------------------------------
__global__ __launch_bounds__(256) void zfill_kernel(float* __restrict__ out) {
  int idx = blockIdx.x * 256 + threadIdx.x;   // grid covers exactly 1492992
  int b = idx / 373248, r = idx - b * 373248;
  *reinterpret_cast<float4*>(out + (long)b * 1741824 + 248832 + (long)r * 4) =
      make_float4(0.f, 0.f, 0.f, 0.f);
}

// ---------------------------------------------------------------------------
// Normalize + f16 + transpose level-1 tensors into ws:
// dst[b][i][j][c] f16 = x[b][c][i][j] / (||x[b,:,i,j]|| + eps).
// Block = (tensor, b, i); norms computed in-block (no norms1 dependency).
// LDS-staged with XOR swizzle for coalesced f16 writes.
// ---------------------------------------------------------------------------
__global__ __launch_bounds__(256) void xpose1_kernel(
    const float* __restrict__ x1, const float* __restrict__ x2,
    __fp16* __restrict__ o1, __fp16* __restrict__ o2) {
  int bx = blockIdx.x;                        // 384 = 2 * 4 * 48
  int tz = bx & 1; int rem = bx >> 1;
  int i = rem % 48, b = rem / 48;
  const float* src = tz ? x2 : x1;
  __fp16* dst = (tz ? o2 : o1) + (long)(b * 48 + i) * 16384;  // 64*256
  __shared__ uint32_t lds[64 * 128];          // 64 rows x 512 B
  __shared__ float sred[4][64];
  int t = threadIdx.x;
  int j = t & 63, cg = t >> 6;                // wave = cg
  const float* sp = src + (long)b * 786432 + (long)i * 64 + j;
  // phase 0: per-pixel sum of squares over this thread's 64 channels
  float ss = 0.f;
#pragma unroll 8
  for (int c8 = 0; c8 < 64; ++c8) {
    float v = sp[(long)(cg * 64 + c8) * 3072];
    ss += v * v;
  }
  sred[cg][j] = ss;
  __syncthreads();
  float invv = 1.f / (sqrtf(sred[0][j] + sred[1][j] + sred[2][j] + sred[3][j]) + EPSN);
  // phase 1: re-read (L2-hot), normalize, cvt f16, pack, swizzled LDS store
#pragma unroll
  for (int cb = 0; cb < 8; ++cb) {
    uint32_t pk[4];
#pragma unroll
    for (int e2 = 0; e2 < 4; ++e2) {
      int c0 = cg * 64 + cb * 8 + e2 * 2;
      __fp16 h0 = (__fp16)(sp[(long)c0 * 3072] * invv);
      __fp16 h1 = (__fp16)(sp[(long)(c0 + 1) * 3072] * invv);
      pk[e2] = (uint32_t)__builtin_bit_cast(uint16_t, h0) |
               ((uint32_t)__builtin_bit_cast(uint16_t, h1) << 16);
    }
    int byteoff = j * 512 + ((cg * 128 + cb * 16) ^ ((j & 7) << 4));
    *reinterpret_cast<uint4*>(reinterpret_cast<char*>(lds) + byteoff) =
        make_uint4(pk[0], pk[1], pk[2], pk[3]);
  }
  __syncthreads();
  // phase 2: coalesced 16B writes
#pragma unroll
  for (int rep = 0; rep < 8; ++rep) {
    int idx = rep * 256 + t;
    int jj = idx >> 5, cb = idx & 31;
    int byteoff = jj * 512 + ((cb * 16) ^ ((jj & 7) << 4));
    uint4 val = *reinterpret_cast<const uint4*>(
        reinterpret_cast<const char*>(lds) + byteoff);
    *reinterpret_cast<uint4*>(reinterpret_cast<char*>(dst) + jj * 512 + cb * 16) = val;
  }
}

// ---------------------------------------------------------------------------
// Level 1 via MFMA: 1 wave per (b, i, row-offset o). C[j1][j2] = sum_c
// w1[b,i,j1,c]*w2[b,i+o,j2,c] (64x64x256, f16 in, f32 acc). One GEMM serves
// every (dI,u) with (u-4)*dils[dI]==o; banded epilogue via LDS C-dump.
// Frag layout (m97-validated): lane l -> row/col l&15, k=(l>>4)*8+[0..8).
// ---------------------------------------------------------------------------
__device__ const int OFFS35[35] = {
    0, 1, -1, 2, -2, 3, -3, 4, -4, 5, -5, 6, -6, 8, -8, 9, -9, 10, -10,
    12, -12, 15, -15, 16, -16, 18, -18, 20, -20, 27, -27, 32, -32, 36, -36};

__global__ __launch_bounds__(64) void corr1m_kernel(
    const __fp16* __restrict__ w1, const __fp16* __restrict__ w2,
    float* __restrict__ out) {
  const int dils[6] = {1, 2, 3, 5, 9, 16};
  int bx = blockIdx.x;
  int L = (bx & 7) * 840 + (bx >> 3);         // 6720 = 8 * 840 (bijective)
  int oi = L % 35, i = (L / 35) % 48, b = L / 1680;
  int o = OFFS35[oi];
  int y = i + o;
  if (y < 0 || y >= 48) return;               // outputs covered by zfill
  int l = threadIdx.x;
  int lm = l & 15, lk = l >> 4;
  const __fp16* A = w1 + (long)(b * 48 + i) * 16384;   // [j1][c]
  const __fp16* B = w2 + (long)(b * 48 + y) * 16384;   // [j2][c]
  f32x4 acc[4][4];
#pragma unroll
  for (int tm = 0; tm < 4; ++tm)
#pragma unroll
    for (int tn = 0; tn < 4; ++tn) acc[tm][tn] = (f32x4)0.f;

  for (int ks = 0; ks < 8; ++ks) {
    f16x8 af[4], bf[4];
    int ko = ks * 32 + lk * 8;
#pragma unroll
    for (int tm = 0; tm < 4; ++tm)
      af[tm] = __builtin_bit_cast(f16x8, *reinterpret_cast<const uint4*>(
                   A + (tm * 16 + lm) * 256 + ko));
#pragma unroll
    for (int tn = 0; tn < 4; ++tn)
      bf[tn] = __builtin_bit_cast(f16x8, *reinterpret_cast<const uint4*>(
                   B + (tn * 16 + lm) * 256 + ko));
#pragma unroll
    for (int tm = 0; tm < 4; ++tm)
#pragma unroll
      for (int tn = 0; tn < 4; ++tn)
        acc[tm][tn] = __builtin_amdgcn_mfma_f32_16x16x32_f16(
            af[tm], bf[tn], acc[tm][tn], 0, 0, 0);
  }

  __shared__ float c_lds[64][65];
#pragma unroll
  for (int tm = 0; tm < 4; ++tm)
#pragma unroll
    for (int tn = 0; tn < 4; ++tn)
#pragma unroll
      for (int r = 0; r < 4; ++r)
        c_lds[tm * 16 + lk * 4 + r][tn * 16 + lm] = acc[tm][tn][r];
  LDS_FENCE();

#pragma unroll
  for (int dI = 0; dI < 6; ++dI) {
    int d = dils[dI];
    if (o % d) continue;
    int ud = o / d;
    if (ud < -4 || ud > 4) continue;
    long ob = (long)b * 1741824 + (long)(1 + dI) * 248832 +
              (long)(ud + 4) * 27648 + (long)i * 64 + l;
#pragma unroll
    for (int v = 0; v < 9; ++v) {
      int j2 = l + (v - 4) * d;
      float val = (j2 >= 0 && j2 < 64) ? c_lds[l][j2] : 0.f;
      out[ob + (long)v * 3072] = val;
    }
  }
}

// ---------------------------------------------------------------------------
// Fallback level-1 (round-6 passing kernel) for small ws_size.
// ---------------------------------------------------------------------------
__global__ __launch_bounds__(64) void corr1_kernel(
    const float* __restrict__ x1, const float* __restrict__ x2,
    const float* __restrict__ ws, float* __restrict__ out) {
  int bx = blockIdx.x;
  int L = (bx & 7) * 1296 + (bx >> 3);
  int u = L % 9, dI = (L / 9) % 6, i = (L / 54) % 48, b = L / 2592;
  const int dils[6] = {1, 2, 3, 5, 9, 16};
  int d = dils[dI];
  int y = i + (u - 4) * d;
  int lane = threadIdx.x;
  long ob = (long)b * 1741824 + (long)(1 + dI) * 248832 + (long)u * 27648 +
            (long)i * 64 + lane;
  if (y < 0 || y >= 48) {
#pragma unroll
    for (int v = 0; v < 9; ++v) out[ob + v * 3072] = 0.f;
    return;
  }
  __shared__ uint4 x2t[192];
  x2t[lane] = make_uint4(0, 0, 0, 0);
  x2t[lane + 64] = make_uint4(0, 0, 0, 0);
  x2t[lane + 128] = make_uint4(0, 0, 0, 0);
  float acc[9];
#pragma unroll
  for (int v = 0; v < 9; ++v) acc[v] = 0.f;
  const float* x2row = x2 + (long)b * 786432 + (long)y * 64 + lane;
  const float* x1row = x1 + (long)b * 786432 + (long)i * 64 + lane;
#pragma unroll 1
  for (int cc8 = 0; cc8 < 32; ++cc8) {
    float x1v[8]; uint32_t xb[8];
#pragma unroll
    for (int cc = 0; cc < 8; ++cc) {
      long c = cc8 * 8 + cc;
      xb[cc] = __float_as_uint(x2row[c * 3072]) + 0x8000u;
      x1v[cc] = x1row[c * 3072];
    }
    uint4 pk;
    pk.x = (xb[0] >> 16) | (xb[1] & 0xffff0000u);
    pk.y = (xb[2] >> 16) | (xb[3] & 0xffff0000u);
    pk.z = (xb[4] >> 16) | (xb[5] & 0xffff0000u);
    pk.w = (xb[6] >> 16) | (xb[7] & 0xffff0000u);
    x2t[64 + lane] = pk;
    LDS_FENCE();
#pragma unroll
    for (int v = 0; v < 9; ++v) {
      uint4 q = x2t[64 + lane + (v - 4) * d];
      float s;
      s  = x1v[0] * __uint_as_float(q.x << 16);
      s += x1v[1] * __uint_as_float(q.x & 0xffff0000u);
      s += x1v[2] * __uint_as_float(q.y << 16);
      s += x1v[3] * __uint_as_float(q.y & 0xffff0000u);
      s += x1v[4] * __uint_as_float(q.z << 16);
      s += x1v[5] * __uint_as_float(q.z & 0xffff0000u);
      s += x1v[6] * __uint_as_float(q.w << 16);
      s += x1v[7] * __uint_as_float(q.w & 0xffff0000u);
      acc[v] += s;
    }
    LDS_FENCE();
  }
  const float* i1 = ws + b * 3072 + i * 64;
  const float* i2 = ws + 12288 + b * 3072 + y * 64;
  float inv1 = i1[lane];
#pragma unroll
  for (int v = 0; v < 9; ++v) {
    int col = lane + (v - 4) * d;
    float i2v = (col >= 0 && col < 64) ? i2[col] : 0.f;
    out[ob + v * 3072] = acc[v] * inv1 * i2v;
  }
}

extern "C" void kernel_launch(void* const* d_in, const int* in_sizes, int n_in,
                              void* d_out, int out_size, void* d_ws, size_t ws_size,
                              hipStream_t stream) {
  const float* x1_0 = (const float*)d_in[0];
  const float* x1_1 = (const float*)d_in[1];
  const float* x2_0 = (const float*)d_in[2];
  const float* x2_1 = (const float*)d_in[3];
  float* out = (float*)d_out;
  float* ws = (float*)d_ws;
  corr0_kernel<<<1728, 256, 0, stream>>>(x1_0, x2_0, out);
  if (ws_size >= 12681216) {
    __fp16* w1h = (__fp16*)((char*)d_ws + 98304);
    __fp16* w2h = w1h + 3145728;              // 4*48*64*256 elems
    zfill_kernel<<<5832, 256, 0, stream>>>(out);
    xpose1_kernel<<<384, 256, 0, stream>>>(x1_1, x2_1, w1h, w2h);
    corr1m_kernel<<<6720, 64, 0, stream>>>(w1h, w2h, out);
  } else {
    norms1_kernel<<<96, 256, 0, stream>>>(x1_1, x2_1, ws);
    corr1_kernel<<<10368, 64, 0, stream>>>(x1_1, x2_1, ws, out);
  }
}

// Round 9
// 123.071 us; speedup vs baseline: 1.7691x; 1.0705x over previous
//
#include <hip/hip_runtime.h>
#include <stdint.h>

#define EPSN 1e-9f

typedef __fp16 f16x8 __attribute__((ext_vector_type(8)));
typedef float f32x4 __attribute__((ext_vector_type(4)));

// Wave-level LDS fence (rule #18: sched_barrier after waitcnt).
#define LDS_FENCE()                                        \
  do {                                                     \
    asm volatile("s_waitcnt lgkmcnt(0)" ::: "memory");     \
    __builtin_amdgcn_sched_barrier(0);                     \
  } while (0)

// ---------------------------------------------------------------------------
// ws layout: [0) inv1_1 [4][3072] f32  [12288) inv2_1 [4][3072] f32
//            byte 98304: w1h [4][48][64][256] f16 (6291456 B)
//            byte 6389760: w2h same                (6291456 B)
// fast path needs 12681216 B total.
// ---------------------------------------------------------------------------

__global__ __launch_bounds__(256) void norms1_kernel(
    const float* __restrict__ x1_1, const float* __restrict__ x2_1,
    float* __restrict__ ws) {
  int p = blockIdx.x * 256 + threadIdx.x;     // 24576 total
  const float* src = (p < 12288) ? x1_1 : x2_1;
  int q = (p < 12288) ? p : p - 12288;
  long base = (long)(q / 3072) * 786432 + (q % 3072);
  float ss = 0.f;
#pragma unroll 8
  for (int c = 0; c < 256; ++c) { float v = src[base + (long)c * 3072]; ss += v * v; }
  ws[p] = 1.f / (sqrtf(ss) + EPSN);
}

// ---------------------------------------------------------------------------
// Level 0 v2: ONE BLOCK PER (b, x2-row y) -> each x2 row read exactly once.
// 768 blocks, 256 thr. Block computes all (i,u) pairs with 4i+u-4==y
// (NI in 1..3). Shuffle scheme identical to the round-6/8 passing kernel,
// replicated per i-candidate. Norms (inv1 per i-row, inv2 for row y) fused.
// ---------------------------------------------------------------------------
__global__ __launch_bounds__(256) void corr0_kernel(
    const float* __restrict__ x1, const float* __restrict__ x2,
    float* __restrict__ out) {
  int bx = blockIdx.x;
  int L = (bx & 7) * 96 + (bx >> 3);          // 768 = 8 * 96 (bijective)
  int y = L % 192, b = L / 192;
  int tid = threadIdx.x;
  int w = tid >> 6, lane = tid & 63;
  int i_lo = (y - 1) / 4; if (i_lo < 0) i_lo = 0;   // ceil((y-4)/4), clamped
  int i_hi = (y + 4) / 4; if (i_hi > 47) i_hi = 47;
  int NI = i_hi - i_lo + 1;                   // 1..3

  __shared__ float red[4][34][64];            // 27 acc + 4 sq + 3 s1 slots
  __shared__ float inv2s[264];                // pads [0..3],[260..263] = 0
  __shared__ float inv1s[3][64];

  float acc[3][9];
#pragma unroll
  for (int r = 0; r < 3; ++r)
#pragma unroll
    for (int v = 0; v < 9; ++v) acc[r][v] = 0.f;
  float sq0 = 0.f, sq1 = 0.f, sq2 = 0.f, sq3 = 0.f;
  float s1[3] = {0.f, 0.f, 0.f};

  const float* x2row = x2 + (long)b * 12582912 + (long)y * 256 + 4 * lane;
  const float* x1p[3];
#pragma unroll
  for (int r = 0; r < 3; ++r) {
    int ir = i_lo + r; if (ir > 47) ir = 47;  // clamp (discarded if r>=NI)
    x1p[r] = x1 + (long)b * 12582912 + (long)(4 * ir) * 256 + 4 * lane;
  }

#pragma unroll 4
  for (int cc = 0; cc < 64; ++cc) {
    long off = (long)(w * 64 + cc) * 49152;
    float4 f = *reinterpret_cast<const float4*>(x2row + off);
    sq0 += f.x * f.x; sq1 += f.y * f.y; sq2 += f.z * f.z; sq3 += f.w * f.w;
#pragma unroll
    for (int r = 0; r < 3; ++r) {
      float xv = x1p[r][off];
      float xr = __shfl_down(xv, 1);          // x1 of lane j+1
      float xl = __shfl_up(xv, 1);            // x1 of lane j-1
      s1[r] += xv * xv;
      acc[r][0] += xr * f.x; acc[r][1] += xr * f.y;
      acc[r][2] += xr * f.z; acc[r][3] += xr * f.w;
      acc[r][4] += xv * f.x; acc[r][5] += xv * f.y;
      acc[r][6] += xv * f.z; acc[r][7] += xv * f.w;
      acc[r][8] += xl * f.x;
    }
  }

  // realign + dump to LDS: acc[v<4](j) lives at lane j-1; acc[8](j) at j+1.
#pragma unroll
  for (int r = 0; r < 3; ++r) {
    red[w][r * 9 + 0][lane] = __shfl_up(acc[r][0], 1);
    red[w][r * 9 + 1][lane] = __shfl_up(acc[r][1], 1);
    red[w][r * 9 + 2][lane] = __shfl_up(acc[r][2], 1);
    red[w][r * 9 + 3][lane] = __shfl_up(acc[r][3], 1);
    red[w][r * 9 + 4][lane] = acc[r][4];
    red[w][r * 9 + 5][lane] = acc[r][5];
    red[w][r * 9 + 6][lane] = acc[r][6];
    red[w][r * 9 + 7][lane] = acc[r][7];
    red[w][r * 9 + 8][lane] = __shfl_down(acc[r][8], 1);
    red[w][31 + r][lane] = s1[r];
  }
  red[w][27][lane] = sq0; red[w][28][lane] = sq1;
  red[w][29][lane] = sq2; red[w][30][lane] = sq3;
  __syncthreads();
  {
    int comp = tid & 3, jj = tid >> 2;        // col = tid (0..255)
    float ss = red[0][27 + comp][jj] + red[1][27 + comp][jj] +
               red[2][27 + comp][jj] + red[3][27 + comp][jj];
    inv2s[4 + tid] = 1.f / (sqrtf(ss) + EPSN);
    if (tid < 4) { inv2s[tid] = 0.f; inv2s[260 + tid] = 0.f; }
    if (tid < 192) {
      int r = tid >> 6, j = tid & 63;
      float t = red[0][31 + r][j] + red[1][31 + r][j] +
                red[2][31 + r][j] + red[3][31 + r][j];
      inv1s[r][j] = 1.f / (sqrtf(t) + EPSN);
    }
  }
  __syncthreads();
  int lim = NI * 576;
  for (int idx = tid; idx < lim; idx += 256) {
    int r = idx / 576, rem = idx - r * 576;
    int v = rem >> 6, j = rem & 63;
    int i_r = i_lo + r;
    int u_r = y - 4 * i_r + 4;                // in [0,8]
    float s = red[0][r * 9 + v][j] + red[1][r * 9 + v][j] +
              red[2][r * 9 + v][j] + red[3][r * 9 + v][j];
    out[(long)b * 1741824 + (long)u_r * 27648 + (long)v * 3072 + i_r * 64 + j] =
        s * inv1s[r][j] * inv2s[4 * j + v];   // 4 + (4j+v-4)
  }
}

// ---------------------------------------------------------------------------
// Zero-fill level-0 outputs with OOB x2 row: (i=0,u=0..3) and (i=47,u=8).
// 4 b * 5 slices * 576 = 11520 floats = 45 blocks * 256.
// ---------------------------------------------------------------------------
__global__ __launch_bounds__(256) void zfill0_kernel(float* __restrict__ out) {
  int idx = blockIdx.x * 256 + threadIdx.x;
  int b = idx / 2880, rem = idx - b * 2880;
  int k = rem / 576, rem2 = rem - k * 576;
  int v = rem2 >> 6, j = rem2 & 63;
  int u = (k < 4) ? k : 8;
  int i = (k < 4) ? 0 : 47;
  out[(long)b * 1741824 + (long)u * 27648 + (long)v * 3072 + i * 64 + j] = 0.f;
}

// ---------------------------------------------------------------------------
// Normalize + f16 + transpose level-1 tensors into ws (unchanged, passing).
// ---------------------------------------------------------------------------
__global__ __launch_bounds__(256) void xpose1_kernel(
    const float* __restrict__ x1, const float* __restrict__ x2,
    __fp16* __restrict__ o1, __fp16* __restrict__ o2) {
  int bx = blockIdx.x;                        // 384 = 2 * 4 * 48
  int tz = bx & 1; int rem = bx >> 1;
  int i = rem % 48, b = rem / 48;
  const float* src = tz ? x2 : x1;
  __fp16* dst = (tz ? o2 : o1) + (long)(b * 48 + i) * 16384;  // 64*256
  __shared__ uint32_t lds[64 * 128];          // 64 rows x 512 B
  __shared__ float sred[4][64];
  int t = threadIdx.x;
  int j = t & 63, cg = t >> 6;                // wave = cg
  const float* sp = src + (long)b * 786432 + (long)i * 64 + j;
  float ss = 0.f;
#pragma unroll 8
  for (int c8 = 0; c8 < 64; ++c8) {
    float v = sp[(long)(cg * 64 + c8) * 3072];
    ss += v * v;
  }
  sred[cg][j] = ss;
  __syncthreads();
  float invv = 1.f / (sqrtf(sred[0][j] + sred[1][j] + sred[2][j] + sred[3][j]) + EPSN);
#pragma unroll
  for (int cb = 0; cb < 8; ++cb) {
    uint32_t pk[4];
#pragma unroll
    for (int e2 = 0; e2 < 4; ++e2) {
      int c0 = cg * 64 + cb * 8 + e2 * 2;
      __fp16 h0 = (__fp16)(sp[(long)c0 * 3072] * invv);
      __fp16 h1 = (__fp16)(sp[(long)(c0 + 1) * 3072] * invv);
      pk[e2] = (uint32_t)__builtin_bit_cast(uint16_t, h0) |
               ((uint32_t)__builtin_bit_cast(uint16_t, h1) << 16);
    }
    int byteoff = j * 512 + ((cg * 128 + cb * 16) ^ ((j & 7) << 4));
    *reinterpret_cast<uint4*>(reinterpret_cast<char*>(lds) + byteoff) =
        make_uint4(pk[0], pk[1], pk[2], pk[3]);
  }
  __syncthreads();
#pragma unroll
  for (int rep = 0; rep < 8; ++rep) {
    int idx = rep * 256 + t;
    int jj = idx >> 5, cb = idx & 31;
    int byteoff = jj * 512 + ((cb * 16) ^ ((jj & 7) << 4));
    uint4 val = *reinterpret_cast<const uint4*>(
        reinterpret_cast<const char*>(lds) + byteoff);
    *reinterpret_cast<uint4*>(reinterpret_cast<char*>(dst) + jj * 512 + cb * 16) = val;
  }
}

// ---------------------------------------------------------------------------
// Level 1 via MFMA, zfill merged: 39 row-offsets (incl. +-48,+-64 which are
// always OOB -> pure zero-writers). Invalid blocks write zeros for their
// (dI,u) mappings; valid blocks run the 64x64x256 GEMM + banded epilogue.
// ---------------------------------------------------------------------------
__device__ const int OFFS39[39] = {
    0, 1, -1, 2, -2, 3, -3, 4, -4, 5, -5, 6, -6, 8, -8, 9, -9, 10, -10,
    12, -12, 15, -15, 16, -16, 18, -18, 20, -20, 27, -27, 32, -32, 36, -36,
    48, -48, 64, -64};

__global__ __launch_bounds__(64) void corr1m_kernel(
    const __fp16* __restrict__ w1, const __fp16* __restrict__ w2,
    float* __restrict__ out) {
  const int dils[6] = {1, 2, 3, 5, 9, 16};
  int bx = blockIdx.x;
  int L = (bx & 7) * 936 + (bx >> 3);         // 7488 = 8 * 936 (bijective)
  int oi = L % 39, i = (L / 39) % 48, b = L / 1872;
  int o = OFFS39[oi];
  int y = i + o;
  bool valid = (y >= 0 && y < 48);
  int l = threadIdx.x;
  __shared__ float c_lds[64][65];

  if (valid) {
    int lm = l & 15, lk = l >> 4;
    const __fp16* A = w1 + (long)(b * 48 + i) * 16384;   // [j1][c]
    const __fp16* B = w2 + (long)(b * 48 + y) * 16384;   // [j2][c]
    f32x4 acc[4][4];
#pragma unroll
    for (int tm = 0; tm < 4; ++tm)
#pragma unroll
      for (int tn = 0; tn < 4; ++tn) acc[tm][tn] = (f32x4)0.f;

    for (int ks = 0; ks < 8; ++ks) {
      f16x8 af[4], bf[4];
      int ko = ks * 32 + lk * 8;
#pragma unroll
      for (int tm = 0; tm < 4; ++tm)
        af[tm] = __builtin_bit_cast(f16x8, *reinterpret_cast<const uint4*>(
                     A + (tm * 16 + lm) * 256 + ko));
#pragma unroll
      for (int tn = 0; tn < 4; ++tn)
        bf[tn] = __builtin_bit_cast(f16x8, *reinterpret_cast<const uint4*>(
                     B + (tn * 16 + lm) * 256 + ko));
#pragma unroll
      for (int tm = 0; tm < 4; ++tm)
#pragma unroll
        for (int tn = 0; tn < 4; ++tn)
          acc[tm][tn] = __builtin_amdgcn_mfma_f32_16x16x32_f16(
              af[tm], bf[tn], acc[tm][tn], 0, 0, 0);
    }
#pragma unroll
    for (int tm = 0; tm < 4; ++tm)
#pragma unroll
      for (int tn = 0; tn < 4; ++tn)
#pragma unroll
        for (int r = 0; r < 4; ++r)
          c_lds[tm * 16 + lk * 4 + r][tn * 16 + lm] = acc[tm][tn][r];
    LDS_FENCE();
  }

#pragma unroll
  for (int dI = 0; dI < 6; ++dI) {
    int d = dils[dI];
    if (o % d) continue;
    int ud = o / d;
    if (ud < -4 || ud > 4) continue;
    long ob = (long)b * 1741824 + (long)(1 + dI) * 248832 +
              (long)(ud + 4) * 27648 + (long)i * 64 + l;
#pragma unroll
    for (int v = 0; v < 9; ++v) {
      float val = 0.f;
      if (valid) {
        int j2 = l + (v - 4) * d;
        val = (j2 >= 0 && j2 < 64) ? c_lds[l][j2] : 0.f;
      }
      out[ob + (long)v * 3072] = val;
    }
  }
}

// ---------------------------------------------------------------------------
// Fallback level-1 (round-6 passing kernel) for small ws_size.
// ---------------------------------------------------------------------------
__global__ __launch_bounds__(64) void corr1_kernel(
    const float* __restrict__ x1, const float* __restrict__ x2,
    const float* __restrict__ ws, float* __restrict__ out) {
  int bx = blockIdx.x;
  int L = (bx & 7) * 1296 + (bx >> 3);
  int u = L % 9, dI = (L / 9) % 6, i = (L / 54) % 48, b = L / 2592;
  const int dils[6] = {1, 2, 3, 5, 9, 16};
  int d = dils[dI];
  int y = i + (u - 4) * d;
  int lane = threadIdx.x;
  long ob = (long)b * 1741824 + (long)(1 + dI) * 248832 + (long)u * 27648 +
            (long)i * 64 + lane;
  if (y < 0 || y >= 48) {
#pragma unroll
    for (int v = 0; v < 9; ++v) out[ob + v * 3072] = 0.f;
    return;
  }
  __shared__ uint4 x2t[192];
  x2t[lane] = make_uint4(0, 0, 0, 0);
  x2t[lane + 64] = make_uint4(0, 0, 0, 0);
  x2t[lane + 128] = make_uint4(0, 0, 0, 0);
  float acc[9];
#pragma unroll
  for (int v = 0; v < 9; ++v) acc[v] = 0.f;
  const float* x2row = x2 + (long)b * 786432 + (long)y * 64 + lane;
  const float* x1row = x1 + (long)b * 786432 + (long)i * 64 + lane;
#pragma unroll 1
  for (int cc8 = 0; cc8 < 32; ++cc8) {
    float x1v[8]; uint32_t xb[8];
#pragma unroll
    for (int cc = 0; cc < 8; ++cc) {
      long c = cc8 * 8 + cc;
      xb[cc] = __float_as_uint(x2row[c * 3072]) + 0x8000u;
      x1v[cc] = x1row[c * 3072];
    }
    uint4 pk;
    pk.x = (xb[0] >> 16) | (xb[1] & 0xffff0000u);
    pk.y = (xb[2] >> 16) | (xb[3] & 0xffff0000u);
    pk.z = (xb[4] >> 16) | (xb[5] & 0xffff0000u);
    pk.w = (xb[6] >> 16) | (xb[7] & 0xffff0000u);
    x2t[64 + lane] = pk;
    LDS_FENCE();
#pragma unroll
    for (int v = 0; v < 9; ++v) {
      uint4 q = x2t[64 + lane + (v - 4) * d];
      float s;
      s  = x1v[0] * __uint_as_float(q.x << 16);
      s += x1v[1] * __uint_as_float(q.x & 0xffff0000u);
      s += x1v[2] * __uint_as_float(q.y << 16);
      s += x1v[3] * __uint_as_float(q.y & 0xffff0000u);
      s += x1v[4] * __uint_as_float(q.z << 16);
      s += x1v[5] * __uint_as_float(q.z & 0xffff0000u);
      s += x1v[6] * __uint_as_float(q.w << 16);
      s += x1v[7] * __uint_as_float(q.w & 0xffff0000u);
      acc[v] += s;
    }
    LDS_FENCE();
  }
  const float* i1 = ws + b * 3072 + i * 64;
  const float* i2 = ws + 12288 + b * 3072 + y * 64;
  float inv1 = i1[lane];
#pragma unroll
  for (int v = 0; v < 9; ++v) {
    int col = lane + (v - 4) * d;
    float i2v = (col >= 0 && col < 64) ? i2[col] : 0.f;
    out[ob + v * 3072] = acc[v] * inv1 * i2v;
  }
}

extern "C" void kernel_launch(void* const* d_in, const int* in_sizes, int n_in,
                              void* d_out, int out_size, void* d_ws, size_t ws_size,
                              hipStream_t stream) {
  const float* x1_0 = (const float*)d_in[0];
  const float* x1_1 = (const float*)d_in[1];
  const float* x2_0 = (const float*)d_in[2];
  const float* x2_1 = (const float*)d_in[3];
  float* out = (float*)d_out;
  float* ws = (float*)d_ws;
  corr0_kernel<<<768, 256, 0, stream>>>(x1_0, x2_0, out);
  zfill0_kernel<<<45, 256, 0, stream>>>(out);
  if (ws_size >= 12681216) {
    __fp16* w1h = (__fp16*)((char*)d_ws + 98304);
    __fp16* w2h = w1h + 3145728;              // 4*48*64*256 elems
    xpose1_kernel<<<384, 256, 0, stream>>>(x1_1, x2_1, w1h, w2h);
    corr1m_kernel<<<7488, 64, 0, stream>>>(w1h, w2h, out);
  } else {
    norms1_kernel<<<96, 256, 0, stream>>>(x1_1, x2_1, ws);
    corr1_kernel<<<10368, 64, 0, stream>>>(x1_1, x2_1, ws, out);
  }
}